// Round 3
// baseline (618.070 us; speedup 1.0000x reference)
//
#include <hip/hip_runtime.h>
#include <math.h>

#define BS 4
#define TSEG 16
#define CC 64
#define DD 64
#define NN 4096
#define KK 32
#define HH 64
#define D5 320

__device__ __forceinline__ float sigm(float x){ return 1.0f/(1.0f+expf(-x)); }
__device__ __forceinline__ float4 tanh4(float4 v){
    return make_float4(tanhf(v.x), tanhf(v.y), tanhf(v.z), tanhf(v.w));
}

// ---------------------------------------------------------------------------
// Kernel 1: pre-scan modulation. One wave per node (4 nodes / 256-thr block).
// All LDS is wave-private -> no __syncthreads anywhere.
// Phase 1 (lane = g*16+hq): fc1 via float4 loads, 80 iters, 16 acc;
//   2-level shfl reduce over d-phase g; fc2 per-lane + 4-level butterfly.
// Phase 2 (lane = d): trace norms, eff_prim store, eff_key -> LDS.
// Phase 2b (lane = b*16+dq): routing dots via float4 + 4-level butterfly.
// ---------------------------------------------------------------------------
__global__ __launch_bounds__(256) void k_pre(
    const float* __restrict__ h_prev,
    const float* __restrict__ pm0,
    const float* __restrict__ trp,
    const float* __restrict__ trk,
    const float* __restrict__ prim,
    const float* __restrict__ keyp,
    const float* __restrict__ dlog,
    const float* __restrict__ fc1w,
    const float* __restrict__ fc1b,
    const float* __restrict__ fc2w,
    const float* __restrict__ fc2b,
    const float* __restrict__ mll,
    const int*  __restrict__ conn,
    float* __restrict__ ws_ep,
    float* __restrict__ ws_rt,
    float* __restrict__ ws_ed)
{
    __shared__ float mod2[4][D5][4];   // [node][d][b]
    __shared__ float ek_s[4][4][DD];   // [node][b][d]
    __shared__ int   cn_s[4][KK];
    const int wid  = threadIdx.x >> 6;
    const int lane = threadIdx.x & 63;
    const int n    = (blockIdx.x << 2) + wid;

    #pragma unroll
    for (int b = 0; b < BS; b++) {
        mod2[wid][lane      ][b] = h_prev[((size_t)b*NN + n)*DD + lane];
        mod2[wid][64  + lane][b] = trp  [((size_t)b*NN + n)*DD + lane];
        mod2[wid][128 + lane][b] = trk  [((size_t)b*NN + n)*DD + lane];
    }
    {
        const float pv = prim[(size_t)n*DD + lane];
        const float kv = keyp[(size_t)n*DD + lane];
        #pragma unroll
        for (int b = 0; b < BS; b++) {
            mod2[wid][192 + lane][b] = pv;
            mod2[wid][256 + lane][b] = kv;
        }
    }
    if (lane < KK) cn_s[wid][lane] = conn[(size_t)n*KK + lane];

    // ---- phase 1: fc1 ----
    const int g  = lane >> 4;   // d-phase 0..3
    const int hq = lane & 15;   // h-chunk: h = 4*hq + j
    float acc[16];
    #pragma unroll
    for (int i = 0; i < 16; i++) acc[i] = 0.f;
    const float* wp = fc1w + (size_t)n*D5*HH + (size_t)g*HH + 4*hq;
    const float* mp = &mod2[wid][g][0];
    #pragma unroll 4
    for (int it = 0; it < 80; it++) {
        const float4 w4 = *(const float4*)(wp + (size_t)it*256);
        const float4 m4 = *(const float4*)(mp + it*16);
        acc[ 0] = fmaf(m4.x, w4.x, acc[ 0]);
        acc[ 1] = fmaf(m4.x, w4.y, acc[ 1]);
        acc[ 2] = fmaf(m4.x, w4.z, acc[ 2]);
        acc[ 3] = fmaf(m4.x, w4.w, acc[ 3]);
        acc[ 4] = fmaf(m4.y, w4.x, acc[ 4]);
        acc[ 5] = fmaf(m4.y, w4.y, acc[ 5]);
        acc[ 6] = fmaf(m4.y, w4.z, acc[ 6]);
        acc[ 7] = fmaf(m4.y, w4.w, acc[ 7]);
        acc[ 8] = fmaf(m4.z, w4.x, acc[ 8]);
        acc[ 9] = fmaf(m4.z, w4.y, acc[ 9]);
        acc[10] = fmaf(m4.z, w4.z, acc[10]);
        acc[11] = fmaf(m4.z, w4.w, acc[11]);
        acc[12] = fmaf(m4.w, w4.x, acc[12]);
        acc[13] = fmaf(m4.w, w4.y, acc[13]);
        acc[14] = fmaf(m4.w, w4.z, acc[14]);
        acc[15] = fmaf(m4.w, w4.w, acc[15]);
    }
    #pragma unroll
    for (int i = 0; i < 16; i++) {
        acc[i] += __shfl_xor(acc[i], 16, 64);
        acc[i] += __shfl_xor(acc[i], 32, 64);
    }
    const float4 b1 = *(const float4*)(fc1b + (size_t)n*HH + 4*hq);
    float x[16];
    #pragma unroll
    for (int b = 0; b < BS; b++) {
        x[b*4+0] = tanhf(acc[b*4+0] + b1.x);
        x[b*4+1] = tanhf(acc[b*4+1] + b1.y);
        x[b*4+2] = tanhf(acc[b*4+2] + b1.z);
        x[b*4+3] = tanhf(acc[b*4+3] + b1.w);
    }

    // ---- fc2 ----
    float f2[12];
    {
        const float4* f2p = (const float4*)(fc2w + (size_t)n*HH*3 + 12*hq);
        const float4 fa = f2p[0], fb = f2p[1], fc = f2p[2];
        f2[0]=fa.x; f2[1]=fa.y; f2[2]=fa.z; f2[3]=fa.w;
        f2[4]=fb.x; f2[5]=fb.y; f2[6]=fb.z; f2[7]=fb.w;
        f2[8]=fc.x; f2[9]=fc.y; f2[10]=fc.z; f2[11]=fc.w;
    }
    float po[12];
    #pragma unroll
    for (int b = 0; b < BS; b++) {
        #pragma unroll
        for (int o = 0; o < 3; o++) {
            po[b*3+o] = x[b*4+0]*f2[0*3+o] + x[b*4+1]*f2[1*3+o]
                      + x[b*4+2]*f2[2*3+o] + x[b*4+3]*f2[3*3+o];
        }
    }
    #pragma unroll
    for (int m = 1; m < 16; m <<= 1) {
        #pragma unroll
        for (int i = 0; i < 12; i++) po[i] += __shfl_xor(po[i], m, 64);
    }
    const float c0 = fc2b[(size_t)n*3+0];
    const float c1 = fc2b[(size_t)n*3+1];
    const float c2 = fc2b[(size_t)n*3+2];
    const float dl  = dlog[n];
    const float mlr = sigm(mll[0]);
    float gp[4], gk[4], ed[4];
    #pragma unroll
    for (int b = 0; b < BS; b++) {
        gp[b] = tanhf(po[b*3+0] + c0);
        gk[b] = tanhf(po[b*3+1] + c1);
        ed[b] = sigm(dl + po[b*3+2] + c2);
    }
    if (lane < 4) {
        const float edsel = (lane==0)?ed[0]:(lane==1)?ed[1]:(lane==2)?ed[2]:ed[3];
        ws_ed[(size_t)lane*NN + n] = edsel;
    }

    // ---- phase 2: lane = d ----
    {
        const int d = lane;
        const float4 tpv = *(const float4*)(&mod2[wid][64  + d][0]);
        const float4 tkv = *(const float4*)(&mod2[wid][128 + d][0]);
        const float  pr  = mod2[wid][192 + d][0];
        const float  kp  = mod2[wid][256 + d][0];
        float tp[4] = {tpv.x, tpv.y, tpv.z, tpv.w};
        float tk[4] = {tkv.x, tkv.y, tkv.z, tkv.w};
        float s2[8];
        #pragma unroll
        for (int b = 0; b < BS; b++) { s2[b] = tp[b]*tp[b]; s2[4+b] = tk[b]*tk[b]; }
        #pragma unroll
        for (int m = 1; m < 64; m <<= 1) {
            #pragma unroll
            for (int i = 0; i < 8; i++) s2[i] += __shfl_xor(s2[i], m, 64);
        }
        #pragma unroll
        for (int b = 0; b < BS; b++) {
            const float np = fmaxf(sqrtf(s2[b]),   1e-8f);
            const float nk = fmaxf(sqrtf(s2[4+b]), 1e-8f);
            const float ep = pr + mlr*gp[b]*(tp[b]/np);
            const float ek = kp + mlr*gk[b]*(tk[b]/nk);
            ws_ep[((size_t)b*NN + n)*DD + d] = ep;
            ek_s[wid][b][d] = ek;
        }
    }

    // ---- phase 2b: routing. lane = bb*16 + dq ----
    {
        const int bb = lane >> 4, dq = lane & 15;
        const float4 ekq = *(const float4*)(&ek_s[wid][bb][4*dq]);
        #pragma unroll 8
        for (int k = 0; k < KK; k++) {
            const int cn = cn_s[wid][k];
            const float4 pm4 = *(const float4*)(pm0 + ((size_t)bb*NN + cn)*DD + 4*dq);
            float rr = ekq.x*pm4.x + ekq.y*pm4.y + ekq.z*pm4.z + ekq.w*pm4.w;
            rr += __shfl_xor(rr, 1, 64);
            rr += __shfl_xor(rr, 2, 64);
            rr += __shfl_xor(rr, 4, 64);
            rr += __shfl_xor(rr, 8, 64);
            if (dq == 0) ws_rt[((size_t)bb*NN + n)*KK + k] = sigm(rr);
        }
    }
}

// ---------------------------------------------------------------------------
// Kernel 2: one scan step. One wave per node (4 nodes / 256-thr block).
// lane = b*16 + dq, each thread owns 4 d (float4 everywhere).
// All LDS wave-private -> no barrier.
// ---------------------------------------------------------------------------
__global__ __launch_bounds__(256) void k_step(
    const float* __restrict__ pm_in,
    float* __restrict__ pm_out,
    const float* __restrict__ h_in,
    float* __restrict__ h_out,
    const float* __restrict__ ws_ep,
    const float* __restrict__ ws_rt,
    const float* __restrict__ ws_ed,
    const float* __restrict__ bw,
    const float* __restrict__ gw,
    const int*  __restrict__ conn,
    const float* __restrict__ cc,
    float* __restrict__ out,
    const int s)
{
    __shared__ float bw_s[4][2048];   // [node][k*64+d]
    __shared__ float gw_s[4][256];    // [node][p*64+d]
    __shared__ float rt_s[4][4][KK];  // [node][b][k]
    __shared__ int   cn_s[4][KK];
    const int wid  = threadIdx.x >> 6;
    const int lane = threadIdx.x & 63;
    const int n    = (blockIdx.x << 2) + wid;

    {
        const float4* src = (const float4*)(bw + (size_t)n*2048);
        float4* dst = (float4*)bw_s[wid];
        #pragma unroll
        for (int i = 0; i < 8; i++) dst[i*64 + lane] = src[i*64 + lane];
        ((float4*)gw_s[wid])[lane] = ((const float4*)(gw + (size_t)n*256))[lane];
        rt_s[wid][lane>>5][lane&31] =
            ws_rt[((size_t)(lane>>5)*NN + n)*KK + (lane&31)];
        rt_s[wid][2+(lane>>5)][lane&31] =
            ws_rt[((size_t)(2+(lane>>5))*NN + n)*KK + (lane&31)];
        if (lane < KK) cn_s[wid][lane] = conn[(size_t)n*KK + lane];
    }

    const int b = lane >> 4, dq = lane & 15;
    const int d0 = 4*dq;
    const size_t bnd = ((size_t)b*NN + n)*DD + d0;

    float4 bs[4];
    #pragma unroll
    for (int j = 0; j < 4; j++) bs[j] = make_float4(0.f,0.f,0.f,0.f);
    #pragma unroll
    for (int k = 0; k < KK; k++) {
        const int cn = cn_s[wid][k];
        const float4 nm = *(const float4*)(pm_in + ((size_t)b*NN + cn)*DD + d0);
        const float  w  = rt_s[wid][b][k];
        const float4 bv = *(const float4*)(&bw_s[wid][k*DD + d0]);
        const int j = k >> 3;
        bs[j].x = fmaf(w*nm.x, bv.x, bs[j].x);
        bs[j].y = fmaf(w*nm.y, bv.y, bs[j].y);
        bs[j].z = fmaf(w*nm.z, bv.z, bs[j].z);
        bs[j].w = fmaf(w*nm.w, bv.w, bs[j].w);
    }
    float4 gs = make_float4(0.f,0.f,0.f,0.f);
    #pragma unroll
    for (int j = 0; j < 4; j++) {
        const float4 br = tanh4(bs[j]);
        const float4 gv = *(const float4*)(&gw_s[wid][j*DD + d0]);
        gs.x = fmaf(br.x, gv.x, gs.x);
        gs.y = fmaf(br.y, gv.y, gs.y);
        gs.z = fmaf(br.z, gv.z, gs.z);
        gs.w = fmaf(br.w, gv.w, gs.w);
    }
    float4 recv = tanh4(gs);
    if (n < CC) {
        const float4 cv = *(const float4*)(cc + (size_t)((b*TSEG + 4*s)*CC + n)*DD + d0);
        recv.x += cv.x; recv.y += cv.y; recv.z += cv.z; recv.w += cv.w;
    }
    const float edv = ws_ed[(size_t)b*NN + n];
    float4 h = *(const float4*)(h_in + bnd);
    h.x = edv*h.x + (1.f-edv)*recv.x;
    h.y = edv*h.y + (1.f-edv)*recv.y;
    h.z = edv*h.z + (1.f-edv)*recv.z;
    h.w = edv*h.w + (1.f-edv)*recv.w;
    *(float4*)(h_out + bnd) = h;
    const float4 ep = *(const float4*)(ws_ep + bnd);
    const float4 pm = tanh4(make_float4(h.x*ep.x, h.y*ep.y, h.z*ep.z, h.w*ep.w));
    *(float4*)(pm_out + bnd) = pm;
    if (n < CC) {
        #pragma unroll
        for (int r = 0; r < 4; r++)
            *(float4*)(out + (size_t)((b*TSEG + 4*s + r)*CC + n)*DD + d0) = pm;
    }
}

extern "C" void kernel_launch(void* const* d_in, const int* in_sizes, int n_in,
                              void* d_out, int out_size, void* d_ws, size_t ws_size,
                              hipStream_t stream) {
    const float* cc    = (const float*)d_in[0];
    const float* h_prev= (const float*)d_in[1];
    const float* pm0   = (const float*)d_in[2];
    const float* trp   = (const float*)d_in[3];
    const float* trk   = (const float*)d_in[4];
    const float* prim  = (const float*)d_in[5];
    const float* keyp  = (const float*)d_in[6];
    const float* dlog  = (const float*)d_in[7];
    const float* bw    = (const float*)d_in[8];
    const float* gw    = (const float*)d_in[9];
    const float* fc1w  = (const float*)d_in[10];
    const float* fc1b  = (const float*)d_in[11];
    const float* fc2w  = (const float*)d_in[12];
    const float* fc2b  = (const float*)d_in[13];
    const float* mll   = (const float*)d_in[14];
    const int*   conn  = (const int*)d_in[15];
    float* out = (float*)d_out;

    float* ws   = (float*)d_ws;
    const size_t BND = (size_t)BS*NN*DD;          // 1048576
    float* ws_h  = ws;
    float* ws_ep = ws + BND;
    float* msgA  = ws + 2*BND;
    float* msgB  = ws + 3*BND;
    float* ws_rt = ws + 4*BND;                    // BS*NN*KK = 524288
    float* ws_ed = ws + 4*BND + (size_t)BS*NN*KK; // BS*NN   = 16384

    k_pre<<<NN/4, 256, 0, stream>>>(h_prev, pm0, trp, trk, prim, keyp, dlog,
                                    fc1w, fc1b, fc2w, fc2b, mll, conn,
                                    ws_ep, ws_rt, ws_ed);

    k_step<<<NN/4, 256, 0, stream>>>(pm0,  msgA, h_prev, ws_h, ws_ep, ws_rt, ws_ed,
                                     bw, gw, conn, cc, out, 0);
    k_step<<<NN/4, 256, 0, stream>>>(msgA, msgB, ws_h, ws_h, ws_ep, ws_rt, ws_ed,
                                     bw, gw, conn, cc, out, 1);
    k_step<<<NN/4, 256, 0, stream>>>(msgB, msgA, ws_h, ws_h, ws_ep, ws_rt, ws_ed,
                                     bw, gw, conn, cc, out, 2);
    k_step<<<NN/4, 256, 0, stream>>>(msgA, msgB, ws_h, ws_h, ws_ep, ws_rt, ws_ed,
                                     bw, gw, conn, cc, out, 3);
}